// Round 1
// baseline (330.773 us; speedup 1.0000x reference)
//
#include <hip/hip_runtime.h>
#include <cstdint>

// GATGraphRegressor: 2-layer GAT (4-head then 1-head) + global mean pool + linear.
// Structure: device-built CSR over dst, wave-per-node gather aggregation
// (softmax via max-pass + unnormalized-weight sum, divide at end).

__device__ __forceinline__ float leaky02(float x) { return x > 0.f ? x : 0.2f * x; }

// ---------------- CSR build ----------------
__global__ void count_kernel(const int* __restrict__ dst, int* __restrict__ cnt, int E) {
    int e = blockIdx.x * blockDim.x + threadIdx.x;
    if (e < E) atomicAdd(&cnt[dst[e]], 1);
}

constexpr int SCAN_CHUNK = 20;  // 1024*20 = 20480 >= N=20000
__global__ __launch_bounds__(1024) void scan_kernel(const int* __restrict__ cnt,
                                                    int* __restrict__ row_ptr, int N) {
    __shared__ int lds[1024];
    const int tid = threadIdx.x;
    int c[SCAN_CHUNK];
    const int base = tid * SCAN_CHUNK;
    int loc = 0;
#pragma unroll
    for (int i = 0; i < SCAN_CHUNK; i++) {
        int idx = base + i;
        int v = (idx < N) ? cnt[idx] : 0;
        c[i] = v;
        loc += v;
    }
    lds[tid] = loc;
    __syncthreads();
    for (int off = 1; off < 1024; off <<= 1) {
        int v = (tid >= off) ? lds[tid - off] : 0;
        __syncthreads();
        lds[tid] += v;
        __syncthreads();
    }
    int run = (tid > 0) ? lds[tid - 1] : 0;
#pragma unroll
    for (int i = 0; i < SCAN_CHUNK; i++) {
        int idx = base + i;
        if (idx < N) row_ptr[idx] = run;
        run += c[i];
    }
    if (tid == 1023) row_ptr[N] = run;
}

__global__ void fill_kernel(const int* __restrict__ src, const int* __restrict__ dst,
                            const int* __restrict__ row_ptr, int* __restrict__ cursor,
                            int* __restrict__ col, int E) {
    int e = blockIdx.x * blockDim.x + threadIdx.x;
    if (e < E) {
        int d = dst[e];
        int pos = row_ptr[d] + atomicAdd(&cursor[d], 1);
        col[pos] = src[e];
    }
}

// ---------------- SGEMM: C[M,Nc] = A[M,K] @ B[K,Nc] (f32, no bias) ----------------
__global__ __launch_bounds__(256) void sgemm_kernel(const float* __restrict__ A,
                                                    const float* __restrict__ B,
                                                    float* __restrict__ C,
                                                    int M, int K, int Nc) {
    __shared__ __align__(16) float As[32][68];  // transposed: As[k][m]; 68*4=272B, 16B-mult
    __shared__ __align__(16) float Bs[32][68];
    const int tid = threadIdx.x;
    const int bm = blockIdx.x * 64, bn = blockIdx.y * 64;
    const int ty = tid >> 4, tx = tid & 15;
    float acc[4][4] = {};
    for (int k0 = 0; k0 < K; k0 += 32) {
#pragma unroll
        for (int i = 0; i < 8; i++) {
            int idx = tid + i * 256;
            int m = idx >> 5, kk = idx & 31;
            int gm = bm + m;
            if (gm >= M) gm = 0;  // clamp; stores are guarded
            As[kk][m] = A[(size_t)gm * K + k0 + kk];
        }
#pragma unroll
        for (int i = 0; i < 8; i++) {
            int idx = tid + i * 256;
            int kk = idx >> 6, n = idx & 63;
            Bs[kk][n] = B[(size_t)(k0 + kk) * Nc + bn + n];
        }
        __syncthreads();
#pragma unroll
        for (int kk = 0; kk < 32; kk++) {
            float4 a4 = *(const float4*)&As[kk][ty * 4];
            float4 b4 = *(const float4*)&Bs[kk][tx * 4];
            float av[4] = {a4.x, a4.y, a4.z, a4.w};
            float bv[4] = {b4.x, b4.y, b4.z, b4.w};
#pragma unroll
            for (int r = 0; r < 4; r++)
#pragma unroll
                for (int c2 = 0; c2 < 4; c2++) acc[r][c2] += av[r] * bv[c2];
        }
        __syncthreads();
    }
#pragma unroll
    for (int r = 0; r < 4; r++) {
        int gm = bm + ty * 4 + r;
        if (gm < M) {
            float4 o = make_float4(acc[r][0], acc[r][1], acc[r][2], acc[r][3]);
            *(float4*)&C[(size_t)gm * Nc + bn + tx * 4] = o;
        }
    }
}

// ---------------- per-node attention scores: s[v,h] = h[v,h,:].a_src[h,:], d likewise ----
template <int H>
__global__ __launch_bounds__(256) void node_scores_kernel(const float* __restrict__ hbuf,
                                                          const float* __restrict__ asrc,
                                                          const float* __restrict__ adst,
                                                          float* __restrict__ s,
                                                          float* __restrict__ d, int N) {
    constexpr int HC = H * 64;
    const int wid = threadIdx.x >> 6, lane = threadIdx.x & 63;
    const int v = blockIdx.x * 4 + wid;
    if (v >= N) return;
    float ps[H], pd[H];
#pragma unroll
    for (int h = 0; h < H; h++) {
        float hv = hbuf[(size_t)v * HC + h * 64 + lane];
        ps[h] = hv * asrc[h * 64 + lane];
        pd[h] = hv * adst[h * 64 + lane];
    }
#pragma unroll
    for (int off = 32; off > 0; off >>= 1) {
#pragma unroll
        for (int h = 0; h < H; h++) {
            ps[h] += __shfl_xor(ps[h], off);
            pd[h] += __shfl_xor(pd[h], off);
        }
    }
    if (lane == 0) {
#pragma unroll
        for (int h = 0; h < H; h++) {
            s[v * H + h] = ps[h];
            d[v * H + h] = pd[h];
        }
    }
}

// ---------------- GAT aggregation: wave per dst node, lane = channel-in-head --------
// out[v] = elu( (sum_e w_e * h[src_e]) / (sum_e w_e) + bias ), w_e = exp(leaky(s+d) - max)
// POOL variant fuses: dot with W_lin, atomic add into per-graph sum/count.
template <int H, bool POOL>
__global__ __launch_bounds__(256) void gat_agg_kernel(
    const float* __restrict__ hbuf, const float* __restrict__ ssc,
    const float* __restrict__ dsc, const int* __restrict__ row_ptr,
    const int* __restrict__ col, const float* __restrict__ bias,
    float* __restrict__ out, const float* __restrict__ Wlin,
    const int* __restrict__ batch, float* __restrict__ gsum,
    float* __restrict__ gcnt, int N) {
    constexpr int HC = H * 64;
    const int wid = threadIdx.x >> 6, lane = threadIdx.x & 63;
    const int v = blockIdx.x * 4 + wid;
    if (v >= N) return;
    const int begin = row_ptr[v], end = row_ptr[v + 1];
    float sv[H], dv[H], m[H];
#pragma unroll
    for (int h = 0; h < H; h++) {
        sv[h] = ssc[v * H + h];
        dv[h] = dsc[v * H + h];
        m[h] = leaky02(sv[h] + dv[h]);  // self-loop logit
    }
    // max pass (lane-parallel over edges)
    for (int i = begin + lane; i < end; i += 64) {
        int s = col[i];
#pragma unroll
        for (int h = 0; h < H; h++) {
            float l = leaky02(ssc[s * H + h] + dv[h]);
            m[h] = fmaxf(m[h], l);
        }
    }
#pragma unroll
    for (int off = 32; off > 0; off >>= 1)
#pragma unroll
        for (int h = 0; h < H; h++) m[h] = fmaxf(m[h], __shfl_xor(m[h], off));
    // weighted-sum pass. Self-loop first.
    float den[H], acc[H];
#pragma unroll
    for (int h = 0; h < H; h++) {
        float w = expf(leaky02(sv[h] + dv[h]) - m[h]);
        den[h] = w;
        acc[h] = w * hbuf[(size_t)v * HC + h * 64 + lane];
    }
    for (int base = begin; base < end; base += 64) {
        int i = base + lane;
        int msrc = (i < end) ? col[i] : 0;
        float mw[H];
#pragma unroll
        for (int h = 0; h < H; h++) {
            float l = leaky02(ssc[msrc * H + h] + dv[h]);
            mw[h] = (i < end) ? expf(l - m[h]) : 0.f;
        }
        int n = min(64, end - base);
        for (int j = 0; j < n; j++) {
            int s = __shfl(msrc, j);
#pragma unroll
            for (int h = 0; h < H; h++) {
                float w = __shfl(mw[h], j);
                den[h] += w;
                acc[h] += w * hbuf[(size_t)s * HC + h * 64 + lane];
            }
        }
    }
    if constexpr (!POOL) {
#pragma unroll
        for (int h = 0; h < H; h++) {
            float r = acc[h] / den[h] + bias[h * 64 + lane];
            r = r > 0.f ? r : expm1f(r);  // ELU
            out[(size_t)v * HC + h * 64 + lane] = r;
        }
    } else {
        float r = acc[0] / den[0] + bias[lane];
        r = r > 0.f ? r : expm1f(r);
        float p = r * Wlin[lane];
#pragma unroll
        for (int off = 32; off > 0; off >>= 1) p += __shfl_xor(p, off);
        if (lane == 0) {
            int g = batch[v];
            atomicAdd(&gsum[g], p);
            atomicAdd(&gcnt[g], 1.f);
        }
    }
}

__global__ void finalize_kernel(const float* __restrict__ gsum, const float* __restrict__ gcnt,
                                const float* __restrict__ blin, float* __restrict__ outp, int G) {
    int g = blockIdx.x * blockDim.x + threadIdx.x;
    if (g < G) outp[g] = gsum[g] / fmaxf(gcnt[g], 1.f) + blin[0];
}

extern "C" void kernel_launch(void* const* d_in, const int* in_sizes, int n_in,
                              void* d_out, int out_size, void* d_ws, size_t ws_size,
                              hipStream_t stream) {
    const float* x      = (const float*)d_in[0];
    const int*   ei     = (const int*)d_in[1];
    const int*   batch  = (const int*)d_in[2];
    const float* W1     = (const float*)d_in[3];
    const float* a_src1 = (const float*)d_in[4];
    const float* a_dst1 = (const float*)d_in[5];
    const float* b1     = (const float*)d_in[6];
    const float* W2     = (const float*)d_in[7];
    const float* a_src2 = (const float*)d_in[8];
    const float* a_dst2 = (const float*)d_in[9];
    const float* b2     = (const float*)d_in[10];
    const float* Wlin   = (const float*)d_in[11];
    const float* blin   = (const float*)d_in[12];

    const int N = in_sizes[2];      // 20000 nodes
    const int E = in_sizes[1] / 2;  // 320000 edges (self-loops handled implicitly)
    const int G = out_size;         // 64 graphs
    const int* src = ei;
    const int* dst = ei + E;

    char* ws = (char*)d_ws;
    size_t off = 0;
    auto carve = [&](size_t bytes) -> char* {
        char* p = ws + off;
        off = (off + bytes + 255) & ~(size_t)255;
        return p;
    };
    float* h1      = (float*)carve((size_t)N * 256 * 4);  // x@W1 (no bias)
    float* out1    = (float*)carve((size_t)N * 256 * 4);  // elu(conv1)
    float* s1      = (float*)carve((size_t)N * 4 * 4);
    float* d1      = (float*)carve((size_t)N * 4 * 4);
    float* s2      = (float*)carve((size_t)N * 4);
    float* d2      = (float*)carve((size_t)N * 4);
    int*   row_ptr = (int*)carve((size_t)(N + 1) * 4);
    int*   cntcur  = (int*)carve((size_t)2 * N * 4);  // cnt | cursor
    int*   col     = (int*)carve((size_t)E * 4);
    float* gbuf    = (float*)carve((size_t)2 * G * 4);  // gsum | gcnt
    float* h2      = h1;  // h1 dead after conv1 aggregation; reuse for out1@W2
    int* cnt = cntcur;
    int* cursor = cntcur + N;
    float* gsum = gbuf;
    float* gcnt = gbuf + G;

    hipMemsetAsync(cntcur, 0, (size_t)2 * N * 4, stream);
    hipMemsetAsync(gbuf, 0, (size_t)2 * G * 4, stream);

    // CSR over dst
    count_kernel<<<(E + 255) / 256, 256, 0, stream>>>(dst, cnt, E);
    scan_kernel<<<1, 1024, 0, stream>>>(cnt, row_ptr, N);
    fill_kernel<<<(E + 255) / 256, 256, 0, stream>>>(src, dst, row_ptr, cursor, col, E);

    const int nodeBlocks = (N + 3) / 4;
    // conv1
    sgemm_kernel<<<dim3((N + 63) / 64, 256 / 64), 256, 0, stream>>>(x, W1, h1, N, 128, 256);
    node_scores_kernel<4><<<nodeBlocks, 256, 0, stream>>>(h1, a_src1, a_dst1, s1, d1, N);
    gat_agg_kernel<4, false><<<nodeBlocks, 256, 0, stream>>>(h1, s1, d1, row_ptr, col, b1,
                                                             out1, nullptr, nullptr, nullptr,
                                                             nullptr, N);
    // conv2
    sgemm_kernel<<<dim3((N + 63) / 64, 1), 256, 0, stream>>>(out1, W2, h2, N, 256, 64);
    node_scores_kernel<1><<<nodeBlocks, 256, 0, stream>>>(h2, a_src2, a_dst2, s2, d2, N);
    gat_agg_kernel<1, true><<<nodeBlocks, 256, 0, stream>>>(h2, s2, d2, row_ptr, col, b2,
                                                            nullptr, Wlin, batch, gsum, gcnt, N);
    // pooled mean + linear
    finalize_kernel<<<1, 64, 0, stream>>>(gsum, gcnt, blin, (float*)d_out, G);
}

// Round 2
// 311.600 us; speedup vs baseline: 1.0615x; 1.0615x over previous
//
#include <hip/hip_runtime.h>
#include <cstdint>

// GATGraphRegressor: 2-layer GAT (4-head then 1-head) + global mean pool + linear.
// CSR over dst; gather aggregation with per-lane weight recompute (no shfl in
// inner loop), float4 channel vectorization, no max-pass (shift-invariant softmax).

__device__ __forceinline__ float leaky02(float x) { return x > 0.f ? x : 0.2f * x; }
__device__ __forceinline__ float eluf(float x) { return x > 0.f ? x : expm1f(x); }

// ---------------- CSR build ----------------
__global__ void count_kernel(const int* __restrict__ dst, int* __restrict__ cnt, int E) {
    int e = blockIdx.x * blockDim.x + threadIdx.x;
    if (e < E) atomicAdd(&cnt[dst[e]], 1);
}

constexpr int SCAN_CHUNK = 20;  // 1024*20 = 20480 >= N=20000
__global__ __launch_bounds__(1024) void scan_kernel(const int* __restrict__ cnt,
                                                    int* __restrict__ row_ptr, int N) {
    __shared__ int lds[1024];
    const int tid = threadIdx.x;
    int c[SCAN_CHUNK];
    const int base = tid * SCAN_CHUNK;
    int loc = 0;
#pragma unroll
    for (int i = 0; i < SCAN_CHUNK; i++) {
        int idx = base + i;
        int v = (idx < N) ? cnt[idx] : 0;
        c[i] = v;
        loc += v;
    }
    lds[tid] = loc;
    __syncthreads();
    for (int off = 1; off < 1024; off <<= 1) {
        int v = (tid >= off) ? lds[tid - off] : 0;
        __syncthreads();
        lds[tid] += v;
        __syncthreads();
    }
    int run = (tid > 0) ? lds[tid - 1] : 0;
#pragma unroll
    for (int i = 0; i < SCAN_CHUNK; i++) {
        int idx = base + i;
        if (idx < N) row_ptr[idx] = run;
        run += c[i];
    }
    if (tid == 1023) row_ptr[N] = run;
}

__global__ void fill_kernel(const int* __restrict__ src, const int* __restrict__ dst,
                            const int* __restrict__ row_ptr, int* __restrict__ cursor,
                            int* __restrict__ col, int E) {
    int e = blockIdx.x * blockDim.x + threadIdx.x;
    if (e < E) {
        int d = dst[e];
        int pos = row_ptr[d] + atomicAdd(&cursor[d], 1);
        col[pos] = src[e];
    }
}

// ---------------- SGEMM: C[M,Nc] = A[M,K] @ B[K,Nc] (f32) ----------------
__global__ __launch_bounds__(256) void sgemm_kernel(const float* __restrict__ A,
                                                    const float* __restrict__ B,
                                                    float* __restrict__ C,
                                                    int M, int K, int Nc) {
    __shared__ __align__(16) float As[32][68];
    __shared__ __align__(16) float Bs[32][68];
    const int tid = threadIdx.x;
    const int bm = blockIdx.x * 64, bn = blockIdx.y * 64;
    const int ty = tid >> 4, tx = tid & 15;
    float acc[4][4] = {};
    for (int k0 = 0; k0 < K; k0 += 32) {
#pragma unroll
        for (int i = 0; i < 8; i++) {
            int idx = tid + i * 256;
            int m = idx >> 5, kk = idx & 31;
            int gm = bm + m;
            if (gm >= M) gm = 0;
            As[kk][m] = A[(size_t)gm * K + k0 + kk];
        }
#pragma unroll
        for (int i = 0; i < 8; i++) {
            int idx = tid + i * 256;
            int kk = idx >> 6, n = idx & 63;
            Bs[kk][n] = B[(size_t)(k0 + kk) * Nc + bn + n];
        }
        __syncthreads();
#pragma unroll
        for (int kk = 0; kk < 32; kk++) {
            float4 a4 = *(const float4*)&As[kk][ty * 4];
            float4 b4 = *(const float4*)&Bs[kk][tx * 4];
            float av[4] = {a4.x, a4.y, a4.z, a4.w};
            float bv[4] = {b4.x, b4.y, b4.z, b4.w};
#pragma unroll
            for (int r = 0; r < 4; r++)
#pragma unroll
                for (int c2 = 0; c2 < 4; c2++) acc[r][c2] += av[r] * bv[c2];
        }
        __syncthreads();
    }
#pragma unroll
    for (int r = 0; r < 4; r++) {
        int gm = bm + ty * 4 + r;
        if (gm < M) {
            float4 o = make_float4(acc[r][0], acc[r][1], acc[r][2], acc[r][3]);
            *(float4*)&C[(size_t)gm * Nc + bn + tx * 4] = o;
        }
    }
}

// ---------------- per-node attention scores ----------------
template <int H>
__global__ __launch_bounds__(256) void node_scores_kernel(const float* __restrict__ hbuf,
                                                          const float* __restrict__ asrc,
                                                          const float* __restrict__ adst,
                                                          float* __restrict__ s,
                                                          float* __restrict__ d, int N) {
    constexpr int HC = H * 64;
    const int wid = threadIdx.x >> 6, lane = threadIdx.x & 63;
    const int v = blockIdx.x * 4 + wid;
    if (v >= N) return;
    float ps[H], pd[H];
#pragma unroll
    for (int h = 0; h < H; h++) {
        float hv = hbuf[(size_t)v * HC + h * 64 + lane];
        ps[h] = hv * asrc[h * 64 + lane];
        pd[h] = hv * adst[h * 64 + lane];
    }
#pragma unroll
    for (int off = 32; off > 0; off >>= 1) {
#pragma unroll
        for (int h = 0; h < H; h++) {
            ps[h] += __shfl_xor(ps[h], off);
            pd[h] += __shfl_xor(pd[h], off);
        }
    }
    if (lane == 0) {
#pragma unroll
        for (int h = 0; h < H; h++) {
            s[v * H + h] = ps[h];
            d[v * H + h] = pd[h];
        }
    }
}

// ---------------- conv1 aggregation: wave per node, lane owns 4 channels ----------
// head h = lane>>4; weight recomputed per lane (broadcast loads), no shfl.
__global__ __launch_bounds__(256) void gat_agg4_kernel(
    const float* __restrict__ hbuf, const float* __restrict__ ssc,
    const float* __restrict__ dsc, const int* __restrict__ row_ptr,
    const int* __restrict__ col, const float* __restrict__ bias,
    float* __restrict__ out, int N) {
    const int wid = threadIdx.x >> 6, lane = threadIdx.x & 63;
    const int v = blockIdx.x * 4 + wid;
    if (v >= N) return;
    const int hh = lane >> 4;
    const float dvh = dsc[v * 4 + hh];
    const float svh = ssc[v * 4 + hh];
    const int begin = row_ptr[v], end = row_ptr[v + 1];
    // self-loop
    float w = __expf(leaky02(svh + dvh));
    float den = w;
    float4 hv = *(const float4*)&hbuf[(size_t)v * 256 + lane * 4];
    float4 acc = make_float4(w * hv.x, w * hv.y, w * hv.z, w * hv.w);
    int i = begin;
    for (; i + 4 <= end; i += 4) {
        int s0 = col[i], s1 = col[i + 1], s2 = col[i + 2], s3 = col[i + 3];
        float4 h0 = *(const float4*)&hbuf[(size_t)s0 * 256 + lane * 4];
        float4 h1 = *(const float4*)&hbuf[(size_t)s1 * 256 + lane * 4];
        float4 h2 = *(const float4*)&hbuf[(size_t)s2 * 256 + lane * 4];
        float4 h3 = *(const float4*)&hbuf[(size_t)s3 * 256 + lane * 4];
        float w0 = __expf(leaky02(ssc[s0 * 4 + hh] + dvh));
        float w1 = __expf(leaky02(ssc[s1 * 4 + hh] + dvh));
        float w2 = __expf(leaky02(ssc[s2 * 4 + hh] + dvh));
        float w3 = __expf(leaky02(ssc[s3 * 4 + hh] + dvh));
        den += w0 + w1 + w2 + w3;
        acc.x += w0 * h0.x + w1 * h1.x + w2 * h2.x + w3 * h3.x;
        acc.y += w0 * h0.y + w1 * h1.y + w2 * h2.y + w3 * h3.y;
        acc.z += w0 * h0.z + w1 * h1.z + w2 * h2.z + w3 * h3.z;
        acc.w += w0 * h0.w + w1 * h1.w + w2 * h2.w + w3 * h3.w;
    }
    for (; i < end; i++) {
        int s0 = col[i];
        float4 h0 = *(const float4*)&hbuf[(size_t)s0 * 256 + lane * 4];
        float w0 = __expf(leaky02(ssc[s0 * 4 + hh] + dvh));
        den += w0;
        acc.x += w0 * h0.x;
        acc.y += w0 * h0.y;
        acc.z += w0 * h0.z;
        acc.w += w0 * h0.w;
    }
    float4 b4 = *(const float4*)&bias[lane * 4];
    float inv = 1.f / den;
    float4 r;
    r.x = eluf(acc.x * inv + b4.x);
    r.y = eluf(acc.y * inv + b4.y);
    r.z = eluf(acc.z * inv + b4.z);
    r.w = eluf(acc.w * inv + b4.w);
    *(float4*)&out[(size_t)v * 256 + lane * 4] = r;
}

// ---------------- conv2 aggregation (H=1, 64ch) + fused pool: 16 lanes/node -------
__global__ __launch_bounds__(256) void gat_agg1_pool_kernel(
    const float* __restrict__ hbuf, const float* __restrict__ ssc,
    const float* __restrict__ dsc, const int* __restrict__ row_ptr,
    const int* __restrict__ col, const float* __restrict__ bias,
    const float* __restrict__ Wlin, const int* __restrict__ batch,
    float* __restrict__ gsum, int N) {
    const int tid = threadIdx.x;
    const int lane16 = tid & 15;
    const int v = blockIdx.x * 16 + (tid >> 4);  // 16 nodes per 256-thread block
    if (v >= N) return;
    const float dv = dsc[v];
    const int begin = row_ptr[v], end = row_ptr[v + 1];
    float w = __expf(leaky02(ssc[v] + dv));
    float den = w;
    float4 hv = *(const float4*)&hbuf[(size_t)v * 64 + lane16 * 4];
    float4 acc = make_float4(w * hv.x, w * hv.y, w * hv.z, w * hv.w);
    int i = begin;
    for (; i + 4 <= end; i += 4) {
        int s0 = col[i], s1 = col[i + 1], s2 = col[i + 2], s3 = col[i + 3];
        float4 h0 = *(const float4*)&hbuf[(size_t)s0 * 64 + lane16 * 4];
        float4 h1 = *(const float4*)&hbuf[(size_t)s1 * 64 + lane16 * 4];
        float4 h2 = *(const float4*)&hbuf[(size_t)s2 * 64 + lane16 * 4];
        float4 h3 = *(const float4*)&hbuf[(size_t)s3 * 64 + lane16 * 4];
        float w0 = __expf(leaky02(ssc[s0] + dv));
        float w1 = __expf(leaky02(ssc[s1] + dv));
        float w2 = __expf(leaky02(ssc[s2] + dv));
        float w3 = __expf(leaky02(ssc[s3] + dv));
        den += w0 + w1 + w2 + w3;
        acc.x += w0 * h0.x + w1 * h1.x + w2 * h2.x + w3 * h3.x;
        acc.y += w0 * h0.y + w1 * h1.y + w2 * h2.y + w3 * h3.y;
        acc.z += w0 * h0.z + w1 * h1.z + w2 * h2.z + w3 * h3.z;
        acc.w += w0 * h0.w + w1 * h1.w + w2 * h2.w + w3 * h3.w;
    }
    for (; i < end; i++) {
        int s0 = col[i];
        float4 h0 = *(const float4*)&hbuf[(size_t)s0 * 64 + lane16 * 4];
        float w0 = __expf(leaky02(ssc[s0] + dv));
        den += w0;
        acc.x += w0 * h0.x;
        acc.y += w0 * h0.y;
        acc.z += w0 * h0.z;
        acc.w += w0 * h0.w;
    }
    float4 b4 = *(const float4*)&bias[lane16 * 4];
    float4 wl = *(const float4*)&Wlin[lane16 * 4];
    float inv = 1.f / den;
    float p = eluf(acc.x * inv + b4.x) * wl.x + eluf(acc.y * inv + b4.y) * wl.y +
              eluf(acc.z * inv + b4.z) * wl.z + eluf(acc.w * inv + b4.w) * wl.w;
#pragma unroll
    for (int off = 8; off > 0; off >>= 1) p += __shfl_xor(p, off);
    if (lane16 == 0) atomicAdd(&gsum[batch[v]], p);
}

// ---------------- finalize: counts via binary search on sorted batch ----------------
__global__ void finalize_kernel(const float* __restrict__ gsum, const int* __restrict__ batch,
                                const float* __restrict__ blin, float* __restrict__ outp,
                                int N, int G) {
    int g = blockIdx.x * blockDim.x + threadIdx.x;
    if (g >= G) return;
    // lower_bound(batch, g) and lower_bound(batch, g+1)
    int lo = 0, hi = N;
    while (lo < hi) { int mid = (lo + hi) >> 1; if (batch[mid] < g) lo = mid + 1; else hi = mid; }
    int lo2 = lo, hi2 = N;
    while (lo2 < hi2) { int mid = (lo2 + hi2) >> 1; if (batch[mid] < g + 1) lo2 = mid + 1; else hi2 = mid; }
    float cnt = (float)(hi2 - lo);
    outp[g] = gsum[g] / fmaxf(cnt, 1.f) + blin[0];
}

extern "C" void kernel_launch(void* const* d_in, const int* in_sizes, int n_in,
                              void* d_out, int out_size, void* d_ws, size_t ws_size,
                              hipStream_t stream) {
    const float* x      = (const float*)d_in[0];
    const int*   ei     = (const int*)d_in[1];
    const int*   batch  = (const int*)d_in[2];
    const float* W1     = (const float*)d_in[3];
    const float* a_src1 = (const float*)d_in[4];
    const float* a_dst1 = (const float*)d_in[5];
    const float* b1     = (const float*)d_in[6];
    const float* W2     = (const float*)d_in[7];
    const float* a_src2 = (const float*)d_in[8];
    const float* a_dst2 = (const float*)d_in[9];
    const float* b2     = (const float*)d_in[10];
    const float* Wlin   = (const float*)d_in[11];
    const float* blin   = (const float*)d_in[12];

    const int N = in_sizes[2];
    const int E = in_sizes[1] / 2;
    const int G = out_size;
    const int* src = ei;
    const int* dst = ei + E;

    char* ws = (char*)d_ws;
    size_t off = 0;
    auto carve = [&](size_t bytes) -> char* {
        char* p = ws + off;
        off = (off + bytes + 255) & ~(size_t)255;
        return p;
    };
    float* h1      = (float*)carve((size_t)N * 256 * 4);
    float* out1    = (float*)carve((size_t)N * 256 * 4);
    float* s1      = (float*)carve((size_t)N * 4 * 4);
    float* d1      = (float*)carve((size_t)N * 4 * 4);
    float* s2      = (float*)carve((size_t)N * 4);
    float* d2      = (float*)carve((size_t)N * 4);
    int*   row_ptr = (int*)carve((size_t)(N + 1) * 4);
    int*   cntcur  = (int*)carve((size_t)2 * N * 4);
    int*   col     = (int*)carve((size_t)E * 4);
    float* gsum    = (float*)carve((size_t)G * 4);
    float* h2      = h1;  // h1 dead after conv1 aggregation
    int* cnt = cntcur;
    int* cursor = cntcur + N;

    hipMemsetAsync(cntcur, 0, (size_t)2 * N * 4, stream);
    hipMemsetAsync(gsum, 0, (size_t)G * 4, stream);

    count_kernel<<<(E + 255) / 256, 256, 0, stream>>>(dst, cnt, E);
    scan_kernel<<<1, 1024, 0, stream>>>(cnt, row_ptr, N);
    fill_kernel<<<(E + 255) / 256, 256, 0, stream>>>(src, dst, row_ptr, cursor, col, E);

    const int nodeBlocks4 = (N + 3) / 4;
    // conv1
    sgemm_kernel<<<dim3((N + 63) / 64, 256 / 64), 256, 0, stream>>>(x, W1, h1, N, 128, 256);
    node_scores_kernel<4><<<nodeBlocks4, 256, 0, stream>>>(h1, a_src1, a_dst1, s1, d1, N);
    gat_agg4_kernel<<<nodeBlocks4, 256, 0, stream>>>(h1, s1, d1, row_ptr, col, b1, out1, N);
    // conv2
    sgemm_kernel<<<dim3((N + 63) / 64, 1), 256, 0, stream>>>(out1, W2, h2, N, 256, 64);
    node_scores_kernel<1><<<nodeBlocks4, 256, 0, stream>>>(h2, a_src2, a_dst2, s2, d2, N);
    gat_agg1_pool_kernel<<<(N + 15) / 16, 256, 0, stream>>>(h2, s2, d2, row_ptr, col, b2,
                                                            Wlin, batch, gsum, N);
    finalize_kernel<<<1, 64, 0, stream>>>(gsum, batch, blin, (float*)d_out, N, G);
}

// Round 3
// 213.665 us; speedup vs baseline: 1.5481x; 1.4584x over previous
//
#include <hip/hip_runtime.h>
#include <cstdint>

// GATGraphRegressor: 2-layer GAT (4-head then 1-head) + global mean pool + linear.
// CSR over dst; gather aggregation, per-lane weight recompute, no max-pass.
// No global atomics on the pooled output (was 140us of same-line atomic drain):
// per-node scalar store + segmented reduction instead.

__device__ __forceinline__ float leaky02(float x) { return x > 0.f ? x : 0.2f * x; }
__device__ __forceinline__ float eluf(float x) { return x > 0.f ? x : expm1f(x); }

// ---------------- CSR build ----------------
__global__ void count_kernel(const int* __restrict__ dst, int* __restrict__ cnt, int E) {
    int e = blockIdx.x * blockDim.x + threadIdx.x;
    if (e < E) atomicAdd(&cnt[dst[e]], 1);
}

constexpr int SCAN_CHUNK = 20;  // 1024*20 = 20480 >= N=20000
__global__ __launch_bounds__(1024) void scan_kernel(const int* __restrict__ cnt,
                                                    int* __restrict__ row_ptr, int N) {
    __shared__ int lds[1024];
    const int tid = threadIdx.x;
    int c[SCAN_CHUNK];
    const int base = tid * SCAN_CHUNK;
    int loc = 0;
#pragma unroll
    for (int i = 0; i < SCAN_CHUNK; i++) {
        int idx = base + i;
        int v = (idx < N) ? cnt[idx] : 0;
        c[i] = v;
        loc += v;
    }
    lds[tid] = loc;
    __syncthreads();
    for (int off = 1; off < 1024; off <<= 1) {
        int v = (tid >= off) ? lds[tid - off] : 0;
        __syncthreads();
        lds[tid] += v;
        __syncthreads();
    }
    int run = (tid > 0) ? lds[tid - 1] : 0;
#pragma unroll
    for (int i = 0; i < SCAN_CHUNK; i++) {
        int idx = base + i;
        if (idx < N) row_ptr[idx] = run;
        run += c[i];
    }
    if (tid == 1023) row_ptr[N] = run;
}

__global__ void fill_kernel(const int* __restrict__ src, const int* __restrict__ dst,
                            const int* __restrict__ row_ptr, int* __restrict__ cursor,
                            int* __restrict__ col, int E) {
    int e = blockIdx.x * blockDim.x + threadIdx.x;
    if (e < E) {
        int d = dst[e];
        int pos = row_ptr[d] + atomicAdd(&cursor[d], 1);
        col[pos] = src[e];
    }
}

// ---------------- SGEMM: C[M,Nc] = A[M,K] @ B[K,Nc] (f32) ----------------
__global__ __launch_bounds__(256) void sgemm_kernel(const float* __restrict__ A,
                                                    const float* __restrict__ B,
                                                    float* __restrict__ C,
                                                    int M, int K, int Nc) {
    __shared__ __align__(16) float As[32][68];
    __shared__ __align__(16) float Bs[32][68];
    const int tid = threadIdx.x;
    const int bm = blockIdx.x * 64, bn = blockIdx.y * 64;
    const int ty = tid >> 4, tx = tid & 15;
    float acc[4][4] = {};
    for (int k0 = 0; k0 < K; k0 += 32) {
#pragma unroll
        for (int i = 0; i < 8; i++) {
            int idx = tid + i * 256;
            int m = idx >> 5, kk = idx & 31;
            int gm = bm + m;
            if (gm >= M) gm = 0;
            As[kk][m] = A[(size_t)gm * K + k0 + kk];
        }
#pragma unroll
        for (int i = 0; i < 8; i++) {
            int idx = tid + i * 256;
            int kk = idx >> 6, n = idx & 63;
            Bs[kk][n] = B[(size_t)(k0 + kk) * Nc + bn + n];
        }
        __syncthreads();
#pragma unroll
        for (int kk = 0; kk < 32; kk++) {
            float4 a4 = *(const float4*)&As[kk][ty * 4];
            float4 b4 = *(const float4*)&Bs[kk][tx * 4];
            float av[4] = {a4.x, a4.y, a4.z, a4.w};
            float bv[4] = {b4.x, b4.y, b4.z, b4.w};
#pragma unroll
            for (int r = 0; r < 4; r++)
#pragma unroll
                for (int c2 = 0; c2 < 4; c2++) acc[r][c2] += av[r] * bv[c2];
        }
        __syncthreads();
    }
#pragma unroll
    for (int r = 0; r < 4; r++) {
        int gm = bm + ty * 4 + r;
        if (gm < M) {
            float4 o = make_float4(acc[r][0], acc[r][1], acc[r][2], acc[r][3]);
            *(float4*)&C[(size_t)gm * Nc + bn + tx * 4] = o;
        }
    }
}

// ---------------- per-node attention scores ----------------
template <int H>
__global__ __launch_bounds__(256) void node_scores_kernel(const float* __restrict__ hbuf,
                                                          const float* __restrict__ asrc,
                                                          const float* __restrict__ adst,
                                                          float* __restrict__ s,
                                                          float* __restrict__ d, int N) {
    constexpr int HC = H * 64;
    const int wid = threadIdx.x >> 6, lane = threadIdx.x & 63;
    const int v = blockIdx.x * 4 + wid;
    if (v >= N) return;
    float ps[H], pd[H];
#pragma unroll
    for (int h = 0; h < H; h++) {
        float hv = hbuf[(size_t)v * HC + h * 64 + lane];
        ps[h] = hv * asrc[h * 64 + lane];
        pd[h] = hv * adst[h * 64 + lane];
    }
#pragma unroll
    for (int off = 32; off > 0; off >>= 1) {
#pragma unroll
        for (int h = 0; h < H; h++) {
            ps[h] += __shfl_xor(ps[h], off);
            pd[h] += __shfl_xor(pd[h], off);
        }
    }
    if (lane == 0) {
#pragma unroll
        for (int h = 0; h < H; h++) {
            s[v * H + h] = ps[h];
            d[v * H + h] = pd[h];
        }
    }
}

// ---------------- conv1 aggregation: block (4 waves) per node ----------------
// lane owns 4 channels (64x4=256); wave w takes 8-edge chunks at stride 32.
// 8 gathers + 8 score loads in flight per wave; LDS cross-wave combine.
__global__ __launch_bounds__(256) void gat_agg4_kernel(
    const float* __restrict__ hbuf, const float* __restrict__ ssc,
    const float* __restrict__ dsc, const int* __restrict__ row_ptr,
    const int* __restrict__ col, const float* __restrict__ bias,
    float* __restrict__ out, int N) {
    const int v = blockIdx.x;
    const int wid = threadIdx.x >> 6, lane = threadIdx.x & 63;
    const int hh = lane >> 4;
    const float dvh = dsc[v * 4 + hh];
    const int begin = row_ptr[v], end = row_ptr[v + 1];
    float den = 0.f;
    float4 acc = make_float4(0.f, 0.f, 0.f, 0.f);
    if (wid == 0) {  // self-loop
        float w = __expf(leaky02(ssc[v * 4 + hh] + dvh));
        float4 hv = *(const float4*)&hbuf[(size_t)v * 256 + lane * 4];
        den = w;
        acc = make_float4(w * hv.x, w * hv.y, w * hv.z, w * hv.w);
    }
    for (int base = begin + wid * 8; base < end; base += 32) {
        const int n = end - base;  // >= 1
        int s[8];
#pragma unroll
        for (int j = 0; j < 8; j++) s[j] = col[base + min(j, n - 1)];
        float4 h[8];
#pragma unroll
        for (int j = 0; j < 8; j++) h[j] = *(const float4*)&hbuf[(size_t)s[j] * 256 + lane * 4];
        float we[8];
#pragma unroll
        for (int j = 0; j < 8; j++)
            we[j] = (j < n) ? __expf(leaky02(ssc[s[j] * 4 + hh] + dvh)) : 0.f;
#pragma unroll
        for (int j = 0; j < 8; j++) {
            den += we[j];
            acc.x += we[j] * h[j].x;
            acc.y += we[j] * h[j].y;
            acc.z += we[j] * h[j].z;
            acc.w += we[j] * h[j].w;
        }
    }
    __shared__ __align__(16) float4 accs[256];
    __shared__ float dens[256];
    accs[threadIdx.x] = acc;
    dens[threadIdx.x] = den;
    __syncthreads();
    if (wid == 0) {
#pragma unroll
        for (int w = 1; w < 4; w++) {
            float4 a = accs[w * 64 + lane];
            acc.x += a.x; acc.y += a.y; acc.z += a.z; acc.w += a.w;
            den += dens[w * 64 + lane];
        }
        float4 b4 = *(const float4*)&bias[lane * 4];
        float inv = 1.f / den;
        float4 r;
        r.x = eluf(acc.x * inv + b4.x);
        r.y = eluf(acc.y * inv + b4.y);
        r.z = eluf(acc.z * inv + b4.z);
        r.w = eluf(acc.w * inv + b4.w);
        *(float4*)&out[(size_t)v * 256 + lane * 4] = r;
    }
}

// ---------------- conv2 aggregation (H=1, 64ch) + Wlin dot: 16 lanes/node -------
// Writes per-node scalar pnode[v] (no global atomics).
__global__ __launch_bounds__(256) void gat_agg1_kernel(
    const float* __restrict__ hbuf, const float* __restrict__ ssc,
    const float* __restrict__ dsc, const int* __restrict__ row_ptr,
    const int* __restrict__ col, const float* __restrict__ bias,
    const float* __restrict__ Wlin, float* __restrict__ pnode, int N) {
    const int tid = threadIdx.x;
    const int lane16 = tid & 15;
    const int v = blockIdx.x * 16 + (tid >> 4);
    if (v >= N) return;
    const float dv = dsc[v];
    const int begin = row_ptr[v], end = row_ptr[v + 1];
    float w = __expf(leaky02(ssc[v] + dv));
    float den = w;
    float4 hv = *(const float4*)&hbuf[(size_t)v * 64 + lane16 * 4];
    float4 acc = make_float4(w * hv.x, w * hv.y, w * hv.z, w * hv.w);
    for (int base = begin; base < end; base += 8) {
        const int n = end - base;  // >= 1
        int s[8];
#pragma unroll
        for (int j = 0; j < 8; j++) s[j] = col[base + min(j, n - 1)];
        float4 h[8];
#pragma unroll
        for (int j = 0; j < 8; j++) h[j] = *(const float4*)&hbuf[(size_t)s[j] * 64 + lane16 * 4];
        float we[8];
#pragma unroll
        for (int j = 0; j < 8; j++)
            we[j] = (j < n) ? __expf(leaky02(ssc[s[j]] + dv)) : 0.f;
#pragma unroll
        for (int j = 0; j < 8; j++) {
            den += we[j];
            acc.x += we[j] * h[j].x;
            acc.y += we[j] * h[j].y;
            acc.z += we[j] * h[j].z;
            acc.w += we[j] * h[j].w;
        }
    }
    float4 b4 = *(const float4*)&bias[lane16 * 4];
    float4 wl = *(const float4*)&Wlin[lane16 * 4];
    float inv = 1.f / den;
    float p = eluf(acc.x * inv + b4.x) * wl.x + eluf(acc.y * inv + b4.y) * wl.y +
              eluf(acc.z * inv + b4.z) * wl.z + eluf(acc.w * inv + b4.w) * wl.w;
#pragma unroll
    for (int off = 8; off > 0; off >>= 1) p += __shfl_xor(p, off);
    if (lane16 == 0) pnode[v] = p;
}

// ---------------- finalize: one wave per graph, segmented sum over sorted batch ----
__global__ __launch_bounds__(64) void finalize_kernel(const float* __restrict__ pnode,
                                                      const int* __restrict__ batch,
                                                      const float* __restrict__ blin,
                                                      float* __restrict__ outp, int N, int G) {
    const int g = blockIdx.x;
    const int lane = threadIdx.x;
    int lo = 0, hi = N;
    while (lo < hi) { int mid = (lo + hi) >> 1; if (batch[mid] < g) lo = mid + 1; else hi = mid; }
    int lo2 = lo, hi2 = N;
    while (lo2 < hi2) { int mid = (lo2 + hi2) >> 1; if (batch[mid] < g + 1) lo2 = mid + 1; else hi2 = mid; }
    float s = 0.f;
    for (int i = lo + lane; i < hi2; i += 64) s += pnode[i];
#pragma unroll
    for (int off = 32; off > 0; off >>= 1) s += __shfl_xor(s, off);
    if (lane == 0) {
        float cnt = (float)(hi2 - lo);
        outp[g] = s / fmaxf(cnt, 1.f) + blin[0];
    }
}

extern "C" void kernel_launch(void* const* d_in, const int* in_sizes, int n_in,
                              void* d_out, int out_size, void* d_ws, size_t ws_size,
                              hipStream_t stream) {
    const float* x      = (const float*)d_in[0];
    const int*   ei     = (const int*)d_in[1];
    const int*   batch  = (const int*)d_in[2];
    const float* W1     = (const float*)d_in[3];
    const float* a_src1 = (const float*)d_in[4];
    const float* a_dst1 = (const float*)d_in[5];
    const float* b1     = (const float*)d_in[6];
    const float* W2     = (const float*)d_in[7];
    const float* a_src2 = (const float*)d_in[8];
    const float* a_dst2 = (const float*)d_in[9];
    const float* b2     = (const float*)d_in[10];
    const float* Wlin   = (const float*)d_in[11];
    const float* blin   = (const float*)d_in[12];

    const int N = in_sizes[2];
    const int E = in_sizes[1] / 2;
    const int G = out_size;
    const int* src = ei;
    const int* dst = ei + E;

    char* ws = (char*)d_ws;
    size_t off = 0;
    auto carve = [&](size_t bytes) -> char* {
        char* p = ws + off;
        off = (off + bytes + 255) & ~(size_t)255;
        return p;
    };
    float* h1      = (float*)carve((size_t)N * 256 * 4);
    float* out1    = (float*)carve((size_t)N * 256 * 4);
    float* s1      = (float*)carve((size_t)N * 4 * 4);
    float* d1      = (float*)carve((size_t)N * 4 * 4);
    float* s2      = (float*)carve((size_t)N * 4);
    float* d2      = (float*)carve((size_t)N * 4);
    int*   row_ptr = (int*)carve((size_t)(N + 1) * 4);
    int*   cntcur  = (int*)carve((size_t)2 * N * 4);
    int*   col     = (int*)carve((size_t)E * 4);
    float* pnode   = (float*)carve((size_t)N * 4);
    float* h2      = h1;  // h1 dead after conv1 aggregation
    int* cnt = cntcur;
    int* cursor = cntcur + N;

    hipMemsetAsync(cntcur, 0, (size_t)2 * N * 4, stream);

    count_kernel<<<(E + 255) / 256, 256, 0, stream>>>(dst, cnt, E);
    scan_kernel<<<1, 1024, 0, stream>>>(cnt, row_ptr, N);
    fill_kernel<<<(E + 255) / 256, 256, 0, stream>>>(src, dst, row_ptr, cursor, col, E);

    const int nodeBlocks4 = (N + 3) / 4;
    // conv1
    sgemm_kernel<<<dim3((N + 63) / 64, 256 / 64), 256, 0, stream>>>(x, W1, h1, N, 128, 256);
    node_scores_kernel<4><<<nodeBlocks4, 256, 0, stream>>>(h1, a_src1, a_dst1, s1, d1, N);
    gat_agg4_kernel<<<N, 256, 0, stream>>>(h1, s1, d1, row_ptr, col, b1, out1, N);
    // conv2
    sgemm_kernel<<<dim3((N + 63) / 64, 1), 256, 0, stream>>>(out1, W2, h2, N, 256, 64);
    node_scores_kernel<1><<<nodeBlocks4, 256, 0, stream>>>(h2, a_src2, a_dst2, s2, d2, N);
    gat_agg1_kernel<<<(N + 15) / 16, 256, 0, stream>>>(h2, s2, d2, row_ptr, col, b2,
                                                       Wlin, pnode, N);
    finalize_kernel<<<G, 64, 0, stream>>>(pnode, batch, blin, (float*)d_out, N, G);
}

// Round 4
// 208.885 us; speedup vs baseline: 1.5835x; 1.0229x over previous
//
#include <hip/hip_runtime.h>
#include <cstdint>

// GATGraphRegressor: 2-layer GAT (4-head then 1-head) + global mean pool + linear.
// CSR over dst; gather aggregation with XCD-pinned channel slices:
// block b handles channel-slice (b&7); round-robin block->XCD dispatch makes each
// XCD's gather working set one 128B-per-node slice (2.56MB) -> L2-resident.

__device__ __forceinline__ float leaky02(float x) { return x > 0.f ? x : 0.2f * x; }
__device__ __forceinline__ float eluf(float x) { return x > 0.f ? x : expm1f(x); }

// ---------------- CSR build ----------------
__global__ void count_kernel(const int* __restrict__ dst, int* __restrict__ cnt, int E) {
    int e = blockIdx.x * blockDim.x + threadIdx.x;
    if (e < E) atomicAdd(&cnt[dst[e]], 1);
}

constexpr int SCAN_CHUNK = 20;  // 1024*20 = 20480 >= N=20000
__global__ __launch_bounds__(1024) void scan_kernel(const int* __restrict__ cnt,
                                                    int* __restrict__ row_ptr, int N) {
    __shared__ int lds[1024];
    const int tid = threadIdx.x;
    int c[SCAN_CHUNK];
    const int base = tid * SCAN_CHUNK;
    int loc = 0;
#pragma unroll
    for (int i = 0; i < SCAN_CHUNK; i++) {
        int idx = base + i;
        int v = (idx < N) ? cnt[idx] : 0;
        c[i] = v;
        loc += v;
    }
    lds[tid] = loc;
    __syncthreads();
    for (int off = 1; off < 1024; off <<= 1) {
        int v = (tid >= off) ? lds[tid - off] : 0;
        __syncthreads();
        lds[tid] += v;
        __syncthreads();
    }
    int run = (tid > 0) ? lds[tid - 1] : 0;
#pragma unroll
    for (int i = 0; i < SCAN_CHUNK; i++) {
        int idx = base + i;
        if (idx < N) row_ptr[idx] = run;
        run += c[i];
    }
    if (tid == 1023) row_ptr[N] = run;
}

__global__ void fill_kernel(const int* __restrict__ src, const int* __restrict__ dst,
                            const int* __restrict__ row_ptr, int* __restrict__ cursor,
                            int* __restrict__ col, int E) {
    int e = blockIdx.x * blockDim.x + threadIdx.x;
    if (e < E) {
        int d = dst[e];
        int pos = row_ptr[d] + atomicAdd(&cursor[d], 1);
        col[pos] = src[e];
    }
}

// ---------------- SGEMM: C[M,Nc] = A[M,K] @ B[K,Nc] (f32) ----------------
__global__ __launch_bounds__(256) void sgemm_kernel(const float* __restrict__ A,
                                                    const float* __restrict__ B,
                                                    float* __restrict__ C,
                                                    int M, int K, int Nc) {
    __shared__ __align__(16) float As[32][68];
    __shared__ __align__(16) float Bs[32][68];
    const int tid = threadIdx.x;
    const int bm = blockIdx.x * 64, bn = blockIdx.y * 64;
    const int ty = tid >> 4, tx = tid & 15;
    float acc[4][4] = {};
    for (int k0 = 0; k0 < K; k0 += 32) {
#pragma unroll
        for (int i = 0; i < 8; i++) {
            int idx = tid + i * 256;
            int m = idx >> 5, kk = idx & 31;
            int gm = bm + m;
            if (gm >= M) gm = 0;
            As[kk][m] = A[(size_t)gm * K + k0 + kk];
        }
#pragma unroll
        for (int i = 0; i < 8; i++) {
            int idx = tid + i * 256;
            int kk = idx >> 6, n = idx & 63;
            Bs[kk][n] = B[(size_t)(k0 + kk) * Nc + bn + n];
        }
        __syncthreads();
#pragma unroll
        for (int kk = 0; kk < 32; kk++) {
            float4 a4 = *(const float4*)&As[kk][ty * 4];
            float4 b4 = *(const float4*)&Bs[kk][tx * 4];
            float av[4] = {a4.x, a4.y, a4.z, a4.w};
            float bv[4] = {b4.x, b4.y, b4.z, b4.w};
#pragma unroll
            for (int r = 0; r < 4; r++)
#pragma unroll
                for (int c2 = 0; c2 < 4; c2++) acc[r][c2] += av[r] * bv[c2];
        }
        __syncthreads();
    }
#pragma unroll
    for (int r = 0; r < 4; r++) {
        int gm = bm + ty * 4 + r;
        if (gm < M) {
            float4 o = make_float4(acc[r][0], acc[r][1], acc[r][2], acc[r][3]);
            *(float4*)&C[(size_t)gm * Nc + bn + tx * 4] = o;
        }
    }
}

// ---------------- per-node attention scores ----------------
template <int H>
__global__ __launch_bounds__(256) void node_scores_kernel(const float* __restrict__ hbuf,
                                                          const float* __restrict__ asrc,
                                                          const float* __restrict__ adst,
                                                          float* __restrict__ s,
                                                          float* __restrict__ d, int N) {
    constexpr int HC = H * 64;
    const int wid = threadIdx.x >> 6, lane = threadIdx.x & 63;
    const int v = blockIdx.x * 4 + wid;
    if (v >= N) return;
    float ps[H], pd[H];
#pragma unroll
    for (int h = 0; h < H; h++) {
        float hv = hbuf[(size_t)v * HC + h * 64 + lane];
        ps[h] = hv * asrc[h * 64 + lane];
        pd[h] = hv * adst[h * 64 + lane];
    }
#pragma unroll
    for (int off = 32; off > 0; off >>= 1) {
#pragma unroll
        for (int h = 0; h < H; h++) {
            ps[h] += __shfl_xor(ps[h], off);
            pd[h] += __shfl_xor(pd[h], off);
        }
    }
    if (lane == 0) {
#pragma unroll
        for (int h = 0; h < H; h++) {
            s[v * H + h] = ps[h];
            d[v * H + h] = pd[h];
        }
    }
}

// ---------------- conv1 aggregation, XCD-sliced ----------------
// slice = blockIdx&7 (32 channels = one 128B line/node); 4 waves = 4 nodes.
// Within wave: lane&7 -> channel quad, lane>>3 -> 8-way edge parallel.
__global__ __launch_bounds__(256) void gat_agg4_kernel(
    const float* __restrict__ hbuf, const float* __restrict__ ssc,
    const float* __restrict__ dsc, const int* __restrict__ row_ptr,
    const int* __restrict__ col, const float* __restrict__ bias,
    float* __restrict__ out, int N) {
    const int slice = blockIdx.x & 7;
    const int v = (blockIdx.x >> 3) * 4 + (threadIdx.x >> 6);
    if (v >= N) return;
    const int lane = threadIdx.x & 63;
    const int cq = lane & 7, eg = lane >> 3;
    const int cbase = slice * 32 + cq * 4;
    const int hh = slice >> 1;
    const float dvh = dsc[v * 4 + hh];
    const int begin = row_ptr[v], end = row_ptr[v + 1];
    float den = 0.f;
    float4 acc = make_float4(0.f, 0.f, 0.f, 0.f);
    if (eg == 0) {  // self-loop
        float w = __expf(leaky02(ssc[v * 4 + hh] + dvh));
        float4 hv = *(const float4*)&hbuf[(size_t)v * 256 + cbase];
        den = w;
        acc = make_float4(w * hv.x, w * hv.y, w * hv.z, w * hv.w);
    }
    const int last = end - 1;
    for (int base = begin; base < end; base += 16) {
        int i0 = base + eg, i1 = base + 8 + eg;
        int s0 = col[min(i0, last)], s1 = col[min(i1, last)];
        float4 h0 = *(const float4*)&hbuf[(size_t)s0 * 256 + cbase];
        float4 h1 = *(const float4*)&hbuf[(size_t)s1 * 256 + cbase];
        float w0 = (i0 < end) ? __expf(leaky02(ssc[s0 * 4 + hh] + dvh)) : 0.f;
        float w1 = (i1 < end) ? __expf(leaky02(ssc[s1 * 4 + hh] + dvh)) : 0.f;
        den += w0 + w1;
        acc.x += w0 * h0.x + w1 * h1.x;
        acc.y += w0 * h0.y + w1 * h1.y;
        acc.z += w0 * h0.z + w1 * h1.z;
        acc.w += w0 * h0.w + w1 * h1.w;
    }
#pragma unroll
    for (int m = 8; m <= 32; m <<= 1) {
        acc.x += __shfl_xor(acc.x, m);
        acc.y += __shfl_xor(acc.y, m);
        acc.z += __shfl_xor(acc.z, m);
        acc.w += __shfl_xor(acc.w, m);
        den += __shfl_xor(den, m);
    }
    if (eg == 0) {
        float4 b4 = *(const float4*)&bias[cbase];
        float inv = 1.f / den;
        float4 r;
        r.x = eluf(acc.x * inv + b4.x);
        r.y = eluf(acc.y * inv + b4.y);
        r.z = eluf(acc.z * inv + b4.z);
        r.w = eluf(acc.w * inv + b4.w);
        *(float4*)&out[(size_t)v * 256 + cbase] = r;
    }
}

// ---------------- conv2 aggregation (64ch) + Wlin dot, XCD-sliced (2 halves) ------
// slice = blockIdx&1 (32 of 64 channels); per-slice partial dot written to pn[slice].
__global__ __launch_bounds__(256) void gat_agg1_kernel(
    const float* __restrict__ hbuf, const float* __restrict__ ssc,
    const float* __restrict__ dsc, const int* __restrict__ row_ptr,
    const int* __restrict__ col, const float* __restrict__ bias,
    const float* __restrict__ Wlin, float* __restrict__ pn0,
    float* __restrict__ pn1, int N) {
    const int slice = blockIdx.x & 1;
    const int v = (blockIdx.x >> 1) * 4 + (threadIdx.x >> 6);
    if (v >= N) return;
    const int lane = threadIdx.x & 63;
    const int cq = lane & 7, eg = lane >> 3;
    const int cbase = slice * 32 + cq * 4;
    const float dv = dsc[v];
    const int begin = row_ptr[v], end = row_ptr[v + 1];
    float den = 0.f;
    float4 acc = make_float4(0.f, 0.f, 0.f, 0.f);
    if (eg == 0) {  // self-loop
        float w = __expf(leaky02(ssc[v] + dv));
        float4 hv = *(const float4*)&hbuf[(size_t)v * 64 + cbase];
        den = w;
        acc = make_float4(w * hv.x, w * hv.y, w * hv.z, w * hv.w);
    }
    const int last = end - 1;
    for (int base = begin; base < end; base += 16) {
        int i0 = base + eg, i1 = base + 8 + eg;
        int s0 = col[min(i0, last)], s1 = col[min(i1, last)];
        float4 h0 = *(const float4*)&hbuf[(size_t)s0 * 64 + cbase];
        float4 h1 = *(const float4*)&hbuf[(size_t)s1 * 64 + cbase];
        float w0 = (i0 < end) ? __expf(leaky02(ssc[s0] + dv)) : 0.f;
        float w1 = (i1 < end) ? __expf(leaky02(ssc[s1] + dv)) : 0.f;
        den += w0 + w1;
        acc.x += w0 * h0.x + w1 * h1.x;
        acc.y += w0 * h0.y + w1 * h1.y;
        acc.z += w0 * h0.z + w1 * h1.z;
        acc.w += w0 * h0.w + w1 * h1.w;
    }
#pragma unroll
    for (int m = 8; m <= 32; m <<= 1) {
        acc.x += __shfl_xor(acc.x, m);
        acc.y += __shfl_xor(acc.y, m);
        acc.z += __shfl_xor(acc.z, m);
        acc.w += __shfl_xor(acc.w, m);
        den += __shfl_xor(den, m);
    }
    float p = 0.f;
    if (eg == 0) {
        float4 b4 = *(const float4*)&bias[cbase];
        float4 wl = *(const float4*)&Wlin[cbase];
        float inv = 1.f / den;
        p = eluf(acc.x * inv + b4.x) * wl.x + eluf(acc.y * inv + b4.y) * wl.y +
            eluf(acc.z * inv + b4.z) * wl.z + eluf(acc.w * inv + b4.w) * wl.w;
    }
#pragma unroll
    for (int m = 1; m <= 4; m <<= 1) p += __shfl_xor(p, m);
    if (lane == 0) (slice ? pn1 : pn0)[v] = p;
}

// ---------------- finalize: one wave per graph, segmented sum over sorted batch ----
__global__ __launch_bounds__(64) void finalize_kernel(const float* __restrict__ pn0,
                                                      const float* __restrict__ pn1,
                                                      const int* __restrict__ batch,
                                                      const float* __restrict__ blin,
                                                      float* __restrict__ outp, int N, int G) {
    const int g = blockIdx.x;
    const int lane = threadIdx.x;
    int lo = 0, hi = N;
    while (lo < hi) { int mid = (lo + hi) >> 1; if (batch[mid] < g) lo = mid + 1; else hi = mid; }
    int lo2 = lo, hi2 = N;
    while (lo2 < hi2) { int mid = (lo2 + hi2) >> 1; if (batch[mid] < g + 1) lo2 = mid + 1; else hi2 = mid; }
    float s = 0.f;
    for (int i = lo + lane; i < hi2; i += 64) s += pn0[i] + pn1[i];
#pragma unroll
    for (int off = 32; off > 0; off >>= 1) s += __shfl_xor(s, off);
    if (lane == 0) {
        float cnt = (float)(hi2 - lo);
        outp[g] = s / fmaxf(cnt, 1.f) + blin[0];
    }
}

extern "C" void kernel_launch(void* const* d_in, const int* in_sizes, int n_in,
                              void* d_out, int out_size, void* d_ws, size_t ws_size,
                              hipStream_t stream) {
    const float* x      = (const float*)d_in[0];
    const int*   ei     = (const int*)d_in[1];
    const int*   batch  = (const int*)d_in[2];
    const float* W1     = (const float*)d_in[3];
    const float* a_src1 = (const float*)d_in[4];
    const float* a_dst1 = (const float*)d_in[5];
    const float* b1     = (const float*)d_in[6];
    const float* W2     = (const float*)d_in[7];
    const float* a_src2 = (const float*)d_in[8];
    const float* a_dst2 = (const float*)d_in[9];
    const float* b2     = (const float*)d_in[10];
    const float* Wlin   = (const float*)d_in[11];
    const float* blin   = (const float*)d_in[12];

    const int N = in_sizes[2];
    const int E = in_sizes[1] / 2;
    const int G = out_size;
    const int* src = ei;
    const int* dst = ei + E;

    char* ws = (char*)d_ws;
    size_t off = 0;
    auto carve = [&](size_t bytes) -> char* {
        char* p = ws + off;
        off = (off + bytes + 255) & ~(size_t)255;
        return p;
    };
    float* h1      = (float*)carve((size_t)N * 256 * 4);
    float* out1    = (float*)carve((size_t)N * 256 * 4);
    float* s1      = (float*)carve((size_t)N * 4 * 4);
    float* d1      = (float*)carve((size_t)N * 4 * 4);
    float* s2      = (float*)carve((size_t)N * 4);
    float* d2      = (float*)carve((size_t)N * 4);
    int*   row_ptr = (int*)carve((size_t)(N + 1) * 4);
    int*   cntcur  = (int*)carve((size_t)2 * N * 4);
    int*   col     = (int*)carve((size_t)E * 4);
    float* pn0     = (float*)carve((size_t)N * 4);
    float* pn1     = (float*)carve((size_t)N * 4);
    float* h2      = h1;  // h1 dead after conv1 aggregation
    int* cnt = cntcur;
    int* cursor = cntcur + N;

    hipMemsetAsync(cntcur, 0, (size_t)2 * N * 4, stream);

    count_kernel<<<(E + 255) / 256, 256, 0, stream>>>(dst, cnt, E);
    scan_kernel<<<1, 1024, 0, stream>>>(cnt, row_ptr, N);
    fill_kernel<<<(E + 255) / 256, 256, 0, stream>>>(src, dst, row_ptr, cursor, col, E);

    const int nodeBlocks4 = (N + 3) / 4;
    // conv1
    sgemm_kernel<<<dim3((N + 63) / 64, 256 / 64), 256, 0, stream>>>(x, W1, h1, N, 128, 256);
    node_scores_kernel<4><<<nodeBlocks4, 256, 0, stream>>>(h1, a_src1, a_dst1, s1, d1, N);
    gat_agg4_kernel<<<8 * nodeBlocks4, 256, 0, stream>>>(h1, s1, d1, row_ptr, col, b1, out1, N);
    // conv2
    sgemm_kernel<<<dim3((N + 63) / 64, 1), 256, 0, stream>>>(out1, W2, h2, N, 256, 64);
    node_scores_kernel<1><<<nodeBlocks4, 256, 0, stream>>>(h2, a_src2, a_dst2, s2, d2, N);
    gat_agg1_kernel<<<2 * nodeBlocks4, 256, 0, stream>>>(h2, s2, d2, row_ptr, col, b2,
                                                         Wlin, pn0, pn1, N);
    finalize_kernel<<<G, 64, 0, stream>>>(pn0, pn1, batch, blin, (float*)d_out, N, G);
}

// Round 5
// 178.937 us; speedup vs baseline: 1.8485x; 1.1674x over previous
//
#include <hip/hip_runtime.h>
#include <cstdint>

// GATGraphRegressor: 2-layer GAT (4-head then 1-head) + global mean pool + linear.
// CSR over dst; gather aggregation with XCD-pinned channel slices (block b ->
// slice b&7; round-robin block->XCD makes each XCD's gather set 2.56MB, L2-res).
// Aggregation waves: 8 nodes/wave, lane=(node,ch-quad), per-lane serial edges,
// NO cross-lane reduce (was 91% VALUBusy of butterfly/prologue overhead).

__device__ __forceinline__ float leaky02(float x) { return x > 0.f ? x : 0.2f * x; }
__device__ __forceinline__ float eluf(float x) { return x > 0.f ? x : expm1f(x); }

// ---------------- CSR build ----------------
__global__ void count_kernel(const int* __restrict__ dst, int* __restrict__ cnt, int E) {
    int e = blockIdx.x * blockDim.x + threadIdx.x;
    if (e < E) atomicAdd(&cnt[dst[e]], 1);
}

constexpr int SCAN_CHUNK = 20;  // 1024*20 = 20480 >= N=20000
__global__ __launch_bounds__(1024) void scan_kernel(const int* __restrict__ cnt,
                                                    int* __restrict__ row_ptr, int N) {
    __shared__ int lds[1024];
    const int tid = threadIdx.x;
    int c[SCAN_CHUNK];
    const int base = tid * SCAN_CHUNK;
    int loc = 0;
#pragma unroll
    for (int i = 0; i < SCAN_CHUNK; i++) {
        int idx = base + i;
        int v = (idx < N) ? cnt[idx] : 0;
        c[i] = v;
        loc += v;
    }
    lds[tid] = loc;
    __syncthreads();
    for (int off = 1; off < 1024; off <<= 1) {
        int v = (tid >= off) ? lds[tid - off] : 0;
        __syncthreads();
        lds[tid] += v;
        __syncthreads();
    }
    int run = (tid > 0) ? lds[tid - 1] : 0;
#pragma unroll
    for (int i = 0; i < SCAN_CHUNK; i++) {
        int idx = base + i;
        if (idx < N) row_ptr[idx] = run;
        run += c[i];
    }
    if (tid == 1023) row_ptr[N] = run;
}

__global__ void fill_kernel(const int* __restrict__ src, const int* __restrict__ dst,
                            const int* __restrict__ row_ptr, int* __restrict__ cursor,
                            int* __restrict__ col, int E) {
    int e = blockIdx.x * blockDim.x + threadIdx.x;
    if (e < E) {
        int d = dst[e];
        int pos = row_ptr[d] + atomicAdd(&cursor[d], 1);
        col[pos] = src[e];
    }
}

// ---------------- SGEMM: C[M,Nc] = A[M,K] @ B[K,Nc] (f32) ----------------
__global__ __launch_bounds__(256) void sgemm_kernel(const float* __restrict__ A,
                                                    const float* __restrict__ B,
                                                    float* __restrict__ C,
                                                    int M, int K, int Nc) {
    __shared__ __align__(16) float As[32][68];
    __shared__ __align__(16) float Bs[32][68];
    const int tid = threadIdx.x;
    const int bm = blockIdx.x * 64, bn = blockIdx.y * 64;
    const int ty = tid >> 4, tx = tid & 15;
    float acc[4][4] = {};
    for (int k0 = 0; k0 < K; k0 += 32) {
#pragma unroll
        for (int i = 0; i < 8; i++) {
            int idx = tid + i * 256;
            int m = idx >> 5, kk = idx & 31;
            int gm = bm + m;
            if (gm >= M) gm = 0;
            As[kk][m] = A[(size_t)gm * K + k0 + kk];
        }
#pragma unroll
        for (int i = 0; i < 8; i++) {
            int idx = tid + i * 256;
            int kk = idx >> 6, n = idx & 63;
            Bs[kk][n] = B[(size_t)(k0 + kk) * Nc + bn + n];
        }
        __syncthreads();
#pragma unroll
        for (int kk = 0; kk < 32; kk++) {
            float4 a4 = *(const float4*)&As[kk][ty * 4];
            float4 b4 = *(const float4*)&Bs[kk][tx * 4];
            float av[4] = {a4.x, a4.y, a4.z, a4.w};
            float bv[4] = {b4.x, b4.y, b4.z, b4.w};
#pragma unroll
            for (int r = 0; r < 4; r++)
#pragma unroll
                for (int c2 = 0; c2 < 4; c2++) acc[r][c2] += av[r] * bv[c2];
        }
        __syncthreads();
    }
#pragma unroll
    for (int r = 0; r < 4; r++) {
        int gm = bm + ty * 4 + r;
        if (gm < M) {
            float4 o = make_float4(acc[r][0], acc[r][1], acc[r][2], acc[r][3]);
            *(float4*)&C[(size_t)gm * Nc + bn + tx * 4] = o;
        }
    }
}

// ---------------- per-node attention scores ----------------
template <int H>
__global__ __launch_bounds__(256) void node_scores_kernel(const float* __restrict__ hbuf,
                                                          const float* __restrict__ asrc,
                                                          const float* __restrict__ adst,
                                                          float* __restrict__ s,
                                                          float* __restrict__ d, int N) {
    constexpr int HC = H * 64;
    const int wid = threadIdx.x >> 6, lane = threadIdx.x & 63;
    const int v = blockIdx.x * 4 + wid;
    if (v >= N) return;
    float ps[H], pd[H];
#pragma unroll
    for (int h = 0; h < H; h++) {
        float hv = hbuf[(size_t)v * HC + h * 64 + lane];
        ps[h] = hv * asrc[h * 64 + lane];
        pd[h] = hv * adst[h * 64 + lane];
    }
#pragma unroll
    for (int off = 32; off > 0; off >>= 1) {
#pragma unroll
        for (int h = 0; h < H; h++) {
            ps[h] += __shfl_xor(ps[h], off);
            pd[h] += __shfl_xor(pd[h], off);
        }
    }
    if (lane == 0) {
#pragma unroll
        for (int h = 0; h < H; h++) {
            s[v * H + h] = ps[h];
            d[v * H + h] = pd[h];
        }
    }
}

// ---------------- conv1 aggregation, XCD-sliced, 8 nodes/wave ----------------
// slice = blockIdx&7 (32 ch = one 128B line/node). lane = (node_sub<<3)|cq.
// Each lane serially walks its node's edge list accumulating its 4 channels.
__global__ __launch_bounds__(256) void gat_agg4_kernel(
    const float* __restrict__ hbuf, const float* __restrict__ ssc,
    const float* __restrict__ dsc, const int* __restrict__ row_ptr,
    const int* __restrict__ col, const float* __restrict__ bias,
    float* __restrict__ out, int N) {
    const int slice = blockIdx.x & 7;
    const int lane = threadIdx.x & 63;
    const int cq = lane & 7;
    int v = (blockIdx.x >> 3) * 32 + (threadIdx.x >> 6) * 8 + (lane >> 3);
    const bool valid = v < N;
    if (!valid) v = N - 1;
    const int cbase = slice * 32 + cq * 4;
    const int hh = slice >> 1;
    const float dvh = dsc[v * 4 + hh];
    const int begin = row_ptr[v], end = row_ptr[v + 1];
    // self-loop
    float w = __expf(leaky02(ssc[v * 4 + hh] + dvh));
    float den = w;
    float4 hv = *(const float4*)&hbuf[(size_t)v * 256 + cbase];
    float4 acc = make_float4(w * hv.x, w * hv.y, w * hv.z, w * hv.w);
    const int last = end - 1;
    for (int i = begin; i < end; i += 4) {
        int i1 = i + 1, i2 = i + 2, i3 = i + 3;
        int s0 = col[i];
        int s1 = col[min(i1, last)];
        int s2 = col[min(i2, last)];
        int s3 = col[min(i3, last)];
        float4 h0 = *(const float4*)&hbuf[(size_t)s0 * 256 + cbase];
        float4 h1 = *(const float4*)&hbuf[(size_t)s1 * 256 + cbase];
        float4 h2 = *(const float4*)&hbuf[(size_t)s2 * 256 + cbase];
        float4 h3 = *(const float4*)&hbuf[(size_t)s3 * 256 + cbase];
        float w0 = __expf(leaky02(ssc[s0 * 4 + hh] + dvh));
        float w1 = (i1 < end) ? __expf(leaky02(ssc[s1 * 4 + hh] + dvh)) : 0.f;
        float w2 = (i2 < end) ? __expf(leaky02(ssc[s2 * 4 + hh] + dvh)) : 0.f;
        float w3 = (i3 < end) ? __expf(leaky02(ssc[s3 * 4 + hh] + dvh)) : 0.f;
        den += w0 + w1 + w2 + w3;
        acc.x += w0 * h0.x + w1 * h1.x + w2 * h2.x + w3 * h3.x;
        acc.y += w0 * h0.y + w1 * h1.y + w2 * h2.y + w3 * h3.y;
        acc.z += w0 * h0.z + w1 * h1.z + w2 * h2.z + w3 * h3.z;
        acc.w += w0 * h0.w + w1 * h1.w + w2 * h2.w + w3 * h3.w;
    }
    if (valid) {
        float4 b4 = *(const float4*)&bias[cbase];
        float inv = 1.f / den;
        float4 r;
        r.x = eluf(acc.x * inv + b4.x);
        r.y = eluf(acc.y * inv + b4.y);
        r.z = eluf(acc.z * inv + b4.z);
        r.w = eluf(acc.w * inv + b4.w);
        *(float4*)&out[(size_t)v * 256 + cbase] = r;
    }
}

// ---------------- conv2 aggregation (64ch) + Wlin dot, XCD-sliced, 8 nodes/wave ----
__global__ __launch_bounds__(256) void gat_agg1_kernel(
    const float* __restrict__ hbuf, const float* __restrict__ ssc,
    const float* __restrict__ dsc, const int* __restrict__ row_ptr,
    const int* __restrict__ col, const float* __restrict__ bias,
    const float* __restrict__ Wlin, float* __restrict__ pn0,
    float* __restrict__ pn1, int N) {
    const int slice = blockIdx.x & 1;
    const int lane = threadIdx.x & 63;
    const int cq = lane & 7;
    int v = (blockIdx.x >> 1) * 32 + (threadIdx.x >> 6) * 8 + (lane >> 3);
    const bool valid = v < N;
    if (!valid) v = N - 1;
    const int cbase = slice * 32 + cq * 4;
    const float dv = dsc[v];
    const int begin = row_ptr[v], end = row_ptr[v + 1];
    float w = __expf(leaky02(ssc[v] + dv));
    float den = w;
    float4 hv = *(const float4*)&hbuf[(size_t)v * 64 + cbase];
    float4 acc = make_float4(w * hv.x, w * hv.y, w * hv.z, w * hv.w);
    const int last = end - 1;
    for (int i = begin; i < end; i += 4) {
        int i1 = i + 1, i2 = i + 2, i3 = i + 3;
        int s0 = col[i];
        int s1 = col[min(i1, last)];
        int s2 = col[min(i2, last)];
        int s3 = col[min(i3, last)];
        float4 h0 = *(const float4*)&hbuf[(size_t)s0 * 64 + cbase];
        float4 h1 = *(const float4*)&hbuf[(size_t)s1 * 64 + cbase];
        float4 h2 = *(const float4*)&hbuf[(size_t)s2 * 64 + cbase];
        float4 h3 = *(const float4*)&hbuf[(size_t)s3 * 64 + cbase];
        float w0 = __expf(leaky02(ssc[s0] + dv));
        float w1 = (i1 < end) ? __expf(leaky02(ssc[s1] + dv)) : 0.f;
        float w2 = (i2 < end) ? __expf(leaky02(ssc[s2] + dv)) : 0.f;
        float w3 = (i3 < end) ? __expf(leaky02(ssc[s3] + dv)) : 0.f;
        den += w0 + w1 + w2 + w3;
        acc.x += w0 * h0.x + w1 * h1.x + w2 * h2.x + w3 * h3.x;
        acc.y += w0 * h0.y + w1 * h1.y + w2 * h2.y + w3 * h3.y;
        acc.z += w0 * h0.z + w1 * h1.z + w2 * h2.z + w3 * h3.z;
        acc.w += w0 * h0.w + w1 * h1.w + w2 * h2.w + w3 * h3.w;
    }
    float4 b4 = *(const float4*)&bias[cbase];
    float4 wl = *(const float4*)&Wlin[cbase];
    float inv = 1.f / den;
    float p = eluf(acc.x * inv + b4.x) * wl.x + eluf(acc.y * inv + b4.y) * wl.y +
              eluf(acc.z * inv + b4.z) * wl.z + eluf(acc.w * inv + b4.w) * wl.w;
    // reduce across the 8 cq lanes of this node (low 3 lane bits)
    p += __shfl_xor(p, 1);
    p += __shfl_xor(p, 2);
    p += __shfl_xor(p, 4);
    if (valid && cq == 0) (slice ? pn1 : pn0)[v] = p;
}

// ---------------- finalize: one wave per graph, segmented sum over sorted batch ----
__global__ __launch_bounds__(64) void finalize_kernel(const float* __restrict__ pn0,
                                                      const float* __restrict__ pn1,
                                                      const int* __restrict__ batch,
                                                      const float* __restrict__ blin,
                                                      float* __restrict__ outp, int N, int G) {
    const int g = blockIdx.x;
    const int lane = threadIdx.x;
    int lo = 0, hi = N;
    while (lo < hi) { int mid = (lo + hi) >> 1; if (batch[mid] < g) lo = mid + 1; else hi = mid; }
    int lo2 = lo, hi2 = N;
    while (lo2 < hi2) { int mid = (lo2 + hi2) >> 1; if (batch[mid] < g + 1) lo2 = mid + 1; else hi2 = mid; }
    float s = 0.f;
    for (int i = lo + lane; i < hi2; i += 64) s += pn0[i] + pn1[i];
#pragma unroll
    for (int off = 32; off > 0; off >>= 1) s += __shfl_xor(s, off);
    if (lane == 0) {
        float cnt = (float)(hi2 - lo);
        outp[g] = s / fmaxf(cnt, 1.f) + blin[0];
    }
}

extern "C" void kernel_launch(void* const* d_in, const int* in_sizes, int n_in,
                              void* d_out, int out_size, void* d_ws, size_t ws_size,
                              hipStream_t stream) {
    const float* x      = (const float*)d_in[0];
    const int*   ei     = (const int*)d_in[1];
    const int*   batch  = (const int*)d_in[2];
    const float* W1     = (const float*)d_in[3];
    const float* a_src1 = (const float*)d_in[4];
    const float* a_dst1 = (const float*)d_in[5];
    const float* b1     = (const float*)d_in[6];
    const float* W2     = (const float*)d_in[7];
    const float* a_src2 = (const float*)d_in[8];
    const float* a_dst2 = (const float*)d_in[9];
    const float* b2     = (const float*)d_in[10];
    const float* Wlin   = (const float*)d_in[11];
    const float* blin   = (const float*)d_in[12];

    const int N = in_sizes[2];
    const int E = in_sizes[1] / 2;
    const int G = out_size;
    const int* src = ei;
    const int* dst = ei + E;

    char* ws = (char*)d_ws;
    size_t off = 0;
    auto carve = [&](size_t bytes) -> char* {
        char* p = ws + off;
        off = (off + bytes + 255) & ~(size_t)255;
        return p;
    };
    float* h1      = (float*)carve((size_t)N * 256 * 4);
    float* out1    = (float*)carve((size_t)N * 256 * 4);
    float* s1      = (float*)carve((size_t)N * 4 * 4);
    float* d1      = (float*)carve((size_t)N * 4 * 4);
    float* s2      = (float*)carve((size_t)N * 4);
    float* d2      = (float*)carve((size_t)N * 4);
    int*   row_ptr = (int*)carve((size_t)(N + 1) * 4);
    int*   cntcur  = (int*)carve((size_t)2 * N * 4);
    int*   col     = (int*)carve((size_t)E * 4);
    float* pn0     = (float*)carve((size_t)N * 4);
    float* pn1     = (float*)carve((size_t)N * 4);
    float* h2      = h1;  // h1 dead after conv1 aggregation
    int* cnt = cntcur;
    int* cursor = cntcur + N;

    hipMemsetAsync(cntcur, 0, (size_t)2 * N * 4, stream);

    count_kernel<<<(E + 255) / 256, 256, 0, stream>>>(dst, cnt, E);
    scan_kernel<<<1, 1024, 0, stream>>>(cnt, row_ptr, N);
    fill_kernel<<<(E + 255) / 256, 256, 0, stream>>>(src, dst, row_ptr, cursor, col, E);

    const int nodeBlocks4 = (N + 3) / 4;
    const int nodeGroups32 = (N + 31) / 32;
    // conv1
    sgemm_kernel<<<dim3((N + 63) / 64, 256 / 64), 256, 0, stream>>>(x, W1, h1, N, 128, 256);
    node_scores_kernel<4><<<nodeBlocks4, 256, 0, stream>>>(h1, a_src1, a_dst1, s1, d1, N);
    gat_agg4_kernel<<<8 * nodeGroups32, 256, 0, stream>>>(h1, s1, d1, row_ptr, col, b1, out1, N);
    // conv2
    sgemm_kernel<<<dim3((N + 63) / 64, 1), 256, 0, stream>>>(out1, W2, h2, N, 256, 64);
    node_scores_kernel<1><<<nodeBlocks4, 256, 0, stream>>>(h2, a_src2, a_dst2, s2, d2, N);
    gat_agg1_kernel<<<2 * nodeGroups32, 256, 0, stream>>>(h2, s2, d2, row_ptr, col, b2,
                                                          Wlin, pn0, pn1, N);
    finalize_kernel<<<G, 64, 0, stream>>>(pn0, pn1, batch, blin, (float*)d_out, N, G);
}